// Round 2
// baseline (180.680 us; speedup 1.0000x reference)
//
#include <hip/hip_runtime.h>

// ---------------------------------------------------------------------------
// Convnet: 8 overlapping sections, conv [32x16] x 128 ch, threshold 15, pool
// (400,16), winner-take-all -> single channel index.
//
// R1: per-wave tile M=64 (32t x 2fo) x N=128, block M=256 (32t x 8fo).
//     LDS reads/FLOP cut 1.67x (12 b128 per K32 feed 32 MFMAs). Last t-tile
//     starts at 368 (overlap recompute, pool-OR idempotent) -> no guards.
// ---------------------------------------------------------------------------

using short8 = __attribute__((ext_vector_type(8))) short;
using f32x4  = __attribute__((ext_vector_type(4))) float;

__device__ __forceinline__ unsigned short f2bf(float f) {
  unsigned u = __float_as_uint(f);
  u += 0x7FFFu + ((u >> 16) & 1u);   // RNE
  return (unsigned short)(u >> 16);
}

#define THRESH 15.0f

// ---------------- prep: Wp[((s*64+p)*128 + c)*8 + e] = bf16(W[s][c][k=p*8+e])
__global__ __launch_bounds__(256) void prep_kernel(const float* __restrict__ W,
                                                   unsigned short* __restrict__ Wp,
                                                   int* __restrict__ pool) {
  int t = blockIdx.x * 256 + threadIdx.x;   // 65536 threads
  if (t < 15360) pool[t] = 0;
  int s = t >> 13;
  int r = t & 8191;
  int c = r >> 6;
  int p = r & 63;
  const float* src = W + ((s * 128 + c) * 512 + p * 8);
  float4 v0 = *(const float4*)(src);
  float4 v1 = *(const float4*)(src + 4);
  short8 o;
  o[0] = (short)f2bf(v0.x); o[1] = (short)f2bf(v0.y);
  o[2] = (short)f2bf(v0.z); o[3] = (short)f2bf(v0.w);
  o[4] = (short)f2bf(v1.x); o[5] = (short)f2bf(v1.y);
  o[6] = (short)f2bf(v1.z); o[7] = (short)f2bf(v1.w);
  *(short8*)(Wp + ((s * 64 + p) * 128 + c) * 8) = o;
}

// ---------------- conv + threshold + pool-OR
// grid: 8 s * 13 t-tiles(32) * 30 fo-tiles(8) = 3120 blocks, 256 threads
// block: M = 256 (32 t x 8 fo), N = 128 ch, K = 512 (kt*16+kf)
// wave w: fo offsets {2w, 2w+1}, all 32 t, all 128 ch  -> acc[4][8] f32x4
__global__ __launch_bounds__(256, 3) void conv_pool_kernel(const float* __restrict__ X,
                                                           const unsigned short* __restrict__ Wp,
                                                           int* __restrict__ pool) {
  // 8 fo-shifted copies of the 63-row X patch: copy d holds cols fo0+d..+15,
  // row stride 24 shorts (48 B: b128 16B-aligned)
  __shared__ __align__(16) unsigned short Ash[8 * 1512];   // 24192 B
  __shared__ __align__(16) unsigned short Bsh[8192];       // 16384 B
  __shared__ unsigned poolbits[16];

  const int tid = threadIdx.x;
  const int bid = blockIdx.x;
  const int s   = bid / 390;
  const int rem = bid % 390;
  const int tt  = rem / 30;
  const int ft  = rem % 30;
  const int t0  = (tt == 12) ? 368 : tt * 32;   // last tile overlaps; OR idempotent
  const int fo0 = ft * 8, fp = ft >> 1;
  const int srow = s * 400 + t0;                // max 3168; +62 = 3230 in-bounds

  if (tid < 16) poolbits[tid] = 0;

  // ---- stage A copies: 8 d x 63 r x 2 halves = 1008 b128 writes
  for (int i = tid; i < 1008; i += 256) {
    int d = i / 126, rj = i % 126;
    int r = rj >> 1, h = rj & 1;
    const float* xs = X + (srow + r) * 256 + fo0 + d + h * 8;
    short8 o;
#pragma unroll
    for (int e = 0; e < 8; ++e) o[e] = (short)f2bf(xs[e]);
    *(short8*)&Ash[d * 1512 + r * 24 + h * 8] = o;
  }

  f32x4 acc[4][8];
#pragma unroll
  for (int a = 0; a < 4; ++a)
#pragma unroll
    for (int b = 0; b < 8; ++b) acc[a][b] = (f32x4){0.f, 0.f, 0.f, 0.f};

  const int w = tid >> 6, l = tid & 63;
  const int li = l & 15, q = l >> 4;

  const unsigned short* wbase = Wp + s * 65536;   // 64 packs * 128 ch * 8

  // per-lane bases (immediate-offset friendly)
  const unsigned short* bbase = &Bsh[(q * 128 + li) * 8];
  const unsigned short* abase = &Ash[(2 * w) * 1512 + ((q >> 1) + li) * 24 + (q & 1) * 8];

  __syncthreads();   // A copies + poolbits ready

  for (int ch = 0; ch < 8; ++ch) {            // K chunks of 64
    const unsigned short* gsrc = wbase + ch * 8192;
#pragma unroll
    for (int it = 0; it < 4; ++it) {
      int off = (it * 256 + tid) * 8;         // lane*16B contiguous per wave
      __builtin_amdgcn_global_load_lds(
          (const __attribute__((address_space(1))) void*)(gsrc + off),
          (__attribute__((address_space(3))) void*)(&Bsh[off]), 16, 0, 0);
    }
    __syncthreads();

#pragma unroll
    for (int kb = 0; kb < 2; ++kb) {
      // A frag: lane holds A[m=li][k=q*8+j]; kt = ch*4+kb*2+(q>>1), kf=(q&1)*8+j
      const unsigned short* ab = abase + (ch * 4 + kb * 2) * 24;
      short8 a0 = *(const short8*)(ab);                    // fo +0, t 0..15
      short8 a1 = *(const short8*)(ab + 384);              // fo +0, t 16..31
      short8 a2 = *(const short8*)(ab + 1512);             // fo +1, t 0..15
      short8 a3 = *(const short8*)(ab + 1896);             // fo +1, t 16..31
      const unsigned short* bb = bbase + kb * 4096;        // pack = kb*4+q
#pragma unroll
      for (int nt = 0; nt < 8; ++nt) {
        short8 bfr = *(const short8*)(bb + nt * 128);      // ch n = nt*16+li
        acc[0][nt] = __builtin_amdgcn_mfma_f32_16x16x32_bf16(a0, bfr, acc[0][nt], 0, 0, 0);
        acc[1][nt] = __builtin_amdgcn_mfma_f32_16x16x32_bf16(a1, bfr, acc[1][nt], 0, 0, 0);
        acc[2][nt] = __builtin_amdgcn_mfma_f32_16x16x32_bf16(a2, bfr, acc[2][nt], 0, 0, 0);
        acc[3][nt] = __builtin_amdgcn_mfma_f32_16x16x32_bf16(a3, bfr, acc[3][nt], 0, 0, 0);
      }
    }
    __syncthreads();
  }

  // ---- threshold + OR. Lane holds channels c = nt*16 + li (C/D col = lane&15).
  unsigned sp = 0;
#pragma unroll
  for (int nt = 0; nt < 8; ++nt) {
    float m0 = fmaxf(fmaxf(acc[0][nt][0], acc[0][nt][1]),
                     fmaxf(acc[0][nt][2], acc[0][nt][3]));
    float m1 = fmaxf(fmaxf(acc[1][nt][0], acc[1][nt][1]),
                     fmaxf(acc[1][nt][2], acc[1][nt][3]));
    float m2 = fmaxf(fmaxf(acc[2][nt][0], acc[2][nt][1]),
                     fmaxf(acc[2][nt][2], acc[2][nt][3]));
    float m3 = fmaxf(fmaxf(acc[3][nt][0], acc[3][nt][1]),
                     fmaxf(acc[3][nt][2], acc[3][nt][3]));
    if (fmaxf(fmaxf(m0, m1), fmaxf(m2, m3)) >= THRESH) sp |= (1u << nt);
  }
  sp |= __shfl_xor(sp, 16, 64);
  sp |= __shfl_xor(sp, 32, 64);
  if (l < 16 && sp) atomicOr(&poolbits[l], sp);
  __syncthreads();

  if (tid < 128) {
    unsigned bits = poolbits[tid & 15];
    if ((bits >> (tid >> 4)) & 1)
      pool[(s * 128 + tid) * 15 + fp] = 1;   // benign same-value race across blocks
  }
}

// ---------------- winner (reference get_k_winners semantics)
__global__ __launch_bounds__(256) void winner_kernel(const int* __restrict__ pool,
                                                     float* __restrict__ out) {
  __shared__ int sh_v;
  __shared__ int sh_best;
  int tid = threadIdx.x;
  if (tid == 0) { sh_v = 0; sh_best = 0; }
  __syncthreads();

  int localv = 0;
  for (int p = tid; p < 1920; p += 256) {
    int c = p / 15, f = p % 15;
    int cnt = 0;
    for (int s = 0; s < 8; ++s) cnt += pool[(s * 128 + c) * 15 + f];
    if (cnt > 0) {
      int early = 8 - cnt; if (early > 7) early = 7;
      localv |= pool[(early * 128 + c) * 15 + f];
    }
  }
  if (localv) atomicOr(&sh_v, 1);
  __syncthreads();

  const int v = sh_v * 8;   // trunc.max() * T
  int localbest = 0;
  for (int p = tid; p < 1920; p += 256) {
    int c = p / 15, f = p % 15;
    int cnt = 0;
    for (int s = 0; s < 8; ++s) cnt += pool[(s * 128 + c) * 15 + f];
    int early = 8 - cnt; if (early > 7) early = 7;
    int val = pool[(early * 128 + c) * 15 + f];
    int total = cnt * (val + v);
    int pack = (total << 12) | (4095 - p);   // max total, then smallest flat idx
    if (pack > localbest) localbest = pack;
  }
  atomicMax(&sh_best, localbest);
  __syncthreads();

  if (tid == 0) {
    int total = sh_best >> 12;
    int p = 4095 - (sh_best & 4095);
    int feat = p / 15;
    out[0] = (total != 0) ? (float)feat : -1.0f;
  }
}

// ---------------------------------------------------------------------------
extern "C" void kernel_launch(void* const* d_in, const int* in_sizes, int n_in,
                              void* d_out, int out_size, void* d_ws, size_t ws_size,
                              hipStream_t stream) {
  (void)in_sizes; (void)n_in; (void)out_size; (void)ws_size;
  const float* X = (const float*)d_in[0];
  const float* W = (const float*)d_in[1];
  unsigned short* Wp = (unsigned short*)d_ws;              // 1,048,576 B
  int* pool = (int*)((char*)d_ws + (1 << 20));             // 61,440 B

  prep_kernel<<<256, 256, 0, stream>>>(W, Wp, pool);
  conv_pool_kernel<<<3120, 256, 0, stream>>>(X, Wp, pool);
  winner_kernel<<<1, 256, 0, stream>>>(pool, (float*)d_out);
}

// Round 3
// 137.682 us; speedup vs baseline: 1.3123x; 1.3123x over previous
//
#include <hip/hip_runtime.h>

// ---------------------------------------------------------------------------
// Convnet: 8 overlapping sections, conv [32x16] x 128 ch, threshold 15, pool
// (400,16), winner-take-all -> single channel index.
//
// R2: fix R1's accumulator spill (launch_bounds(256,2) -> 256-VGPR budget),
//     switch to 32x32x16 MFMA (same LDS bytes, -17% MFMA pipe cyc/FLOP,
//     half the issue slots), double-buffer B staging so global_load_lds
//     latency hides behind the MFMA phase.
// ---------------------------------------------------------------------------

using short8 = __attribute__((ext_vector_type(8))) short;
using f32x16 = __attribute__((ext_vector_type(16))) float;

__device__ __forceinline__ unsigned short f2bf(float f) {
  unsigned u = __float_as_uint(f);
  u += 0x7FFFu + ((u >> 16) & 1u);   // RNE
  return (unsigned short)(u >> 16);
}

#define THRESH 15.0f

// ---------------- prep: Wp[((s*64+p)*128 + c)*8 + e] = bf16(W[s][c][k=p*8+e])
__global__ __launch_bounds__(256) void prep_kernel(const float* __restrict__ W,
                                                   unsigned short* __restrict__ Wp,
                                                   int* __restrict__ pool) {
  int t = blockIdx.x * 256 + threadIdx.x;   // 65536 threads
  if (t < 15360) pool[t] = 0;
  int s = t >> 13;
  int r = t & 8191;
  int c = r >> 6;
  int p = r & 63;
  const float* src = W + ((s * 128 + c) * 512 + p * 8);
  float4 v0 = *(const float4*)(src);
  float4 v1 = *(const float4*)(src + 4);
  short8 o;
  o[0] = (short)f2bf(v0.x); o[1] = (short)f2bf(v0.y);
  o[2] = (short)f2bf(v0.z); o[3] = (short)f2bf(v0.w);
  o[4] = (short)f2bf(v1.x); o[5] = (short)f2bf(v1.y);
  o[6] = (short)f2bf(v1.z); o[7] = (short)f2bf(v1.w);
  *(short8*)(Wp + ((s * 64 + p) * 128 + c) * 8) = o;
}

// ---------------- conv + threshold + pool-OR
// grid: 8 s * 13 t-tiles(32) * 30 fo-tiles(8) = 3120 blocks, 256 threads
// block: M = 256 (32 t x 8 fo), N = 128 ch, K = 512 (k = kt*16+kf)
// wave w: fo offsets {2w, 2w+1} -> two 32-row m-tiles (rows = t), N = 128
// 32x32x16 MFMA: A[m=lane&31][k=(lane>>5)*8+j], B[k][n=lane&31], D col=lane&31
__global__ __launch_bounds__(256, 2) void conv_pool_kernel(const float* __restrict__ X,
                                                           const unsigned short* __restrict__ Wp,
                                                           int* __restrict__ pool) {
  // 8 fo-shifted copies of the 63-row X patch: copy d holds cols fo0+d..+15,
  // row stride 24 shorts (48 B: b128 16B-aligned)
  __shared__ __align__(16) unsigned short Ash[8 * 1512];    // 24192 B
  __shared__ __align__(16) unsigned short Bsh[2 * 8192];    // 32768 B (dbuf)
  __shared__ unsigned poolbits[32];

  const int tid = threadIdx.x;
  const int bid = blockIdx.x;
  const int s   = bid / 390;
  const int rem = bid % 390;
  const int tt  = rem / 30;
  const int ft  = rem % 30;
  const int t0  = (tt == 12) ? 368 : tt * 32;   // last tile overlaps; OR idempotent
  const int fo0 = ft * 8, fp = ft >> 1;
  const int srow = s * 400 + t0;                // max 3168; +62 = 3230 in-bounds

  if (tid < 32) poolbits[tid] = 0;

  // ---- stage A copies: 8 d x 63 r x 2 halves = 1008 b128 writes
  for (int i = tid; i < 1008; i += 256) {
    int d = i / 126, rj = i % 126;
    int r = rj >> 1, h = rj & 1;
    const float* xs = X + (srow + r) * 256 + fo0 + d + h * 8;
    short8 o;
#pragma unroll
    for (int e = 0; e < 8; ++e) o[e] = (short)f2bf(xs[e]);
    *(short8*)&Ash[d * 1512 + r * 24 + h * 8] = o;
  }

  f32x16 acc[2][4];
#pragma unroll
  for (int a = 0; a < 2; ++a)
#pragma unroll
    for (int b = 0; b < 4; ++b)
#pragma unroll
      for (int e = 0; e < 16; ++e) acc[a][b][e] = 0.f;

  const int w = tid >> 6, l = tid & 63;
  const int m31 = l & 31, ko = l >> 5;

  const unsigned short* wbase = Wp + s * 65536;   // 64 packs * 128 ch * 8

  // per-lane LDS bases (shorts)
  const unsigned short* abase = &Ash[(2 * w) * 1512 + m31 * 24 + ko * 8];
  const int boff = ko * 1024 + m31 * 8;           // within a B chunk

  // issue B chunk 0 into buf 0 (drained by the next barrier)
  {
    const unsigned short* gsrc = wbase;
#pragma unroll
    for (int it = 0; it < 4; ++it) {
      int off = (it * 256 + tid) * 8;
      __builtin_amdgcn_global_load_lds(
          (const __attribute__((address_space(1))) void*)(gsrc + off),
          (__attribute__((address_space(3))) void*)(&Bsh[off]), 16, 0, 0);
    }
  }
  __syncthreads();   // A copies + chunk 0 + poolbits ready

  for (int ch = 0; ch < 8; ++ch) {              // K chunks of 64 (4 kt each)
    const unsigned short* cur = Bsh + (ch & 1) * 8192;
    if (ch < 7) {                               // prefetch next chunk
      const unsigned short* gsrc = wbase + (ch + 1) * 8192;
      unsigned short* dst = Bsh + ((ch + 1) & 1) * 8192;
#pragma unroll
      for (int it = 0; it < 4; ++it) {
        int off = (it * 256 + tid) * 8;
        __builtin_amdgcn_global_load_lds(
            (const __attribute__((address_space(1))) void*)(gsrc + off),
            (__attribute__((address_space(3))) void*)(dst + off), 16, 0, 0);
      }
    }

    const unsigned short* ab = abase + ch * 96;   // row += 4 kt per chunk
    const unsigned short* bb = cur + boff;
#pragma unroll
    for (int ktr = 0; ktr < 4; ++ktr) {
      short8 a0 = *(const short8*)(ab);             // fo +0, rows t+kt
      short8 a1 = *(const short8*)(ab + 1512);      // fo +1
      ab += 24;
#pragma unroll
      for (int nt = 0; nt < 4; ++nt) {
        short8 bfr = *(const short8*)(bb + ktr * 2048 + nt * 256);  // ch nt*32+m31
        acc[0][nt] = __builtin_amdgcn_mfma_f32_32x32x16_bf16(a0, bfr, acc[0][nt], 0, 0, 0);
        acc[1][nt] = __builtin_amdgcn_mfma_f32_32x32x16_bf16(a1, bfr, acc[1][nt], 0, 0, 0);
      }
    }
    __syncthreads();   // drains prefetch (after ~32 MFMAs of overlap), frees cur
  }

  // ---- threshold + OR. Lane covers channels c = nt*32 + (lane&31).
  unsigned sp = 0;
#pragma unroll
  for (int nt = 0; nt < 4; ++nt) {
    float m0 = -1e30f, m1 = -1e30f;
#pragma unroll
    for (int e = 0; e < 16; ++e) {
      m0 = fmaxf(m0, acc[0][nt][e]);
      m1 = fmaxf(m1, acc[1][nt][e]);
    }
    if (fmaxf(m0, m1) >= THRESH) sp |= (1u << nt);
  }
  sp |= __shfl_xor(sp, 32, 64);   // other half-wave holds the other 16 rows
  if (l < 32 && sp) atomicOr(&poolbits[m31], sp);
  __syncthreads();

  if (tid < 128) {
    unsigned bits = poolbits[tid & 31];
    if ((bits >> (tid >> 5)) & 1)
      pool[(s * 128 + tid) * 15 + fp] = 1;   // benign same-value race across blocks
  }
}

// ---------------- winner (reference get_k_winners semantics)
__global__ __launch_bounds__(256) void winner_kernel(const int* __restrict__ pool,
                                                     float* __restrict__ out) {
  __shared__ int sh_v;
  __shared__ int sh_best;
  int tid = threadIdx.x;
  if (tid == 0) { sh_v = 0; sh_best = 0; }
  __syncthreads();

  int localv = 0;
  for (int p = tid; p < 1920; p += 256) {
    int c = p / 15, f = p % 15;
    int cnt = 0;
    for (int s = 0; s < 8; ++s) cnt += pool[(s * 128 + c) * 15 + f];
    if (cnt > 0) {
      int early = 8 - cnt; if (early > 7) early = 7;
      localv |= pool[(early * 128 + c) * 15 + f];
    }
  }
  if (localv) atomicOr(&sh_v, 1);
  __syncthreads();

  const int v = sh_v * 8;   // trunc.max() * T
  int localbest = 0;
  for (int p = tid; p < 1920; p += 256) {
    int c = p / 15, f = p % 15;
    int cnt = 0;
    for (int s = 0; s < 8; ++s) cnt += pool[(s * 128 + c) * 15 + f];
    int early = 8 - cnt; if (early > 7) early = 7;
    int val = pool[(early * 128 + c) * 15 + f];
    int total = cnt * (val + v);
    int pack = (total << 12) | (4095 - p);   // max total, then smallest flat idx
    if (pack > localbest) localbest = pack;
  }
  atomicMax(&sh_best, localbest);
  __syncthreads();

  if (tid == 0) {
    int total = sh_best >> 12;
    int p = 4095 - (sh_best & 4095);
    int feat = p / 15;
    out[0] = (total != 0) ? (float)feat : -1.0f;
  }
}

// ---------------------------------------------------------------------------
extern "C" void kernel_launch(void* const* d_in, const int* in_sizes, int n_in,
                              void* d_out, int out_size, void* d_ws, size_t ws_size,
                              hipStream_t stream) {
  (void)in_sizes; (void)n_in; (void)out_size; (void)ws_size;
  const float* X = (const float*)d_in[0];
  const float* W = (const float*)d_in[1];
  unsigned short* Wp = (unsigned short*)d_ws;              // 1,048,576 B
  int* pool = (int*)((char*)d_ws + (1 << 20));             // 61,440 B

  prep_kernel<<<256, 256, 0, stream>>>(W, Wp, pool);
  conv_pool_kernel<<<3120, 256, 0, stream>>>(X, Wp, pool);
  winner_kernel<<<1, 256, 0, stream>>>(pool, (float*)d_out);
}